// Round 4
// baseline (189.849 us; speedup 1.0000x reference)
//
#include <hip/hip_runtime.h>

// Problem constants
#define H_ROWS 4096
#define IN_F   4096
#define OUT_F  4096

typedef __bf16 bf16;
typedef __bf16 bf16x4 __attribute__((ext_vector_type(4)));
typedef __bf16 bf16x8 __attribute__((ext_vector_type(8)));
typedef float  f32x4  __attribute__((ext_vector_type(4)));

// ---------------------------------------------------------------------------
// Kernel 1 (R4 rewrite): one block per matrix row; row staged to LDS via
// async global_load_lds (width=16) — NO data VGPRs, NO load->add dependency
// chain, so all 4 x 1KB loads per wave are in flight simultaneously.
// R1-R3 lesson: any VGPR-destined load feeding an accumulator gets
// serialized by the register allocator (VGPR=12 in R3!) -> ~1KB/wave in
// flight -> pinned at ~2.4 TB/s effective. Async LDS staging sidesteps the
// allocator entirely.
//   Element j of row -> output slot t = j&255; float4 index f -> group f&63.
//   Thread tid sums stage[f] for f = tid, tid+256, tid+512, tid+768 (all in
//   group tid&63), then 4 partials per group combine via a 4KB LDS buffer.
// ---------------------------------------------------------------------------
__global__ __launch_bounds__(256) void reduce_kernel(
    const float* __restrict__ x, const float* __restrict__ w,
    bf16* __restrict__ xs, bf16* __restrict__ wsT)
{
    __shared__ float stage[4096];   // 16 KB: the whole row
    __shared__ float part[1024];    // 4 KB: 256 float4 partials
    const int bid = blockIdx.x;
    const float* __restrict__ src = (bid & 1) ? w : x;
    bf16* __restrict__ dst = (bid & 1) ? wsT : xs;
    const int r   = bid >> 1;            // row 0..4095
    const int tid = threadIdx.x;

    const float* __restrict__ rowp = src + r * IN_F;
    #pragma unroll
    for (int c = 0; c < 4; ++c) {
        const int f = c * 256 + tid;     // float4 index within the row
        __builtin_amdgcn_global_load_lds(
            (const __attribute__((address_space(1))) void*)(rowp + f * 4),
            (__attribute__((address_space(3))) void*)(stage + f * 4), 16, 0, 0);
    }
    __syncthreads();   // drains vmcnt

    float4 a0 = ((const float4*)stage)[tid];
    float4 a1 = ((const float4*)stage)[tid + 256];
    float4 a2 = ((const float4*)stage)[tid + 512];
    float4 a3 = ((const float4*)stage)[tid + 768];
    float4 acc;
    acc.x = (a0.x + a1.x) + (a2.x + a3.x);
    acc.y = (a0.y + a1.y) + (a2.y + a3.y);
    acc.z = (a0.z + a1.z) + (a2.z + a3.z);
    acc.w = (a0.w + a1.w) + (a2.w + a3.w);
    ((float4*)part)[tid] = acc;
    __syncthreads();

    if (tid < 64) {
        float4 b0 = ((const float4*)part)[tid];
        float4 b1 = ((const float4*)part)[tid + 64];
        float4 b2 = ((const float4*)part)[tid + 128];
        float4 b3 = ((const float4*)part)[tid + 192];
        float4 t;
        t.x = (b0.x + b1.x) + (b2.x + b3.x);
        t.y = (b0.y + b1.y) + (b2.y + b3.y);
        t.z = (b0.z + b1.z) + (b2.z + b3.z);
        t.w = (b0.w + b1.w) + (b2.w + b3.w);
        bf16x4 o;
        o[0] = (bf16)t.x; o[1] = (bf16)t.y; o[2] = (bf16)t.z; o[3] = (bf16)t.w;
        *(bf16x4*)(dst + r * 256 + tid * 4) = o;
    }
}

// ---------------------------------------------------------------------------
// Kernel 2: NT GEMM  out[m][n] = sum_k A[m][k]*B[n][k] + bias[n]
//   A = xs  (M=4096, K=256) bf16 row-major
//   B = wsT (N=4096, K=256) bf16 row-major
// m97 structure: 128x128 block tile, BK=32, global_load_lds width=16,
// 4 waves in 2x2, each wave 64x64 = 4x4 tiles of 16x16x32 MFMA.
// (unchanged this round — isolating the reduce fix)
// ---------------------------------------------------------------------------
__global__ __launch_bounds__(256) void gemm_bt_kernel(
    const bf16* __restrict__ A, const bf16* __restrict__ B,
    const float* __restrict__ bias, float* __restrict__ out)
{
    __shared__ bf16 As[128 * 32];   // 8 KB
    __shared__ bf16 Bs[128 * 32];   // 8 KB

    const int m0   = blockIdx.y * 128;
    const int n0   = blockIdx.x * 128;
    const int tid  = threadIdx.x;
    const int lane = tid & 63;
    const int w    = tid >> 6;
    const int wm   = (w & 1) * 64;
    const int wn   = (w >> 1) * 64;
    const int l15  = lane & 15;
    const int quad = lane >> 4;

    f32x4 acc[4][4] = {};

    for (int kk = 0; kk < 8; ++kk) {
        const int k0 = kk * 32;
        #pragma unroll
        for (int c = 0; c < 2; ++c) {
            const int chunk = c * 256 + tid;
            const int row   = chunk >> 2;      // 0..127
            const int kc    = chunk & 3;       // 16B chunk within 64B row
            const bf16* ga = A + (m0 + row) * 256 + k0 + kc * 8;
            const bf16* gb = B + (n0 + row) * 256 + k0 + kc * 8;
            __builtin_amdgcn_global_load_lds(
                (const __attribute__((address_space(1))) void*)ga,
                (__attribute__((address_space(3))) void*)(As + chunk * 8), 16, 0, 0);
            __builtin_amdgcn_global_load_lds(
                (const __attribute__((address_space(1))) void*)gb,
                (__attribute__((address_space(3))) void*)(Bs + chunk * 8), 16, 0, 0);
        }
        __syncthreads();

        bf16x8 af[4], bfr[4];
        #pragma unroll
        for (int t = 0; t < 4; ++t) {
            af[t]  = *(const bf16x8*)(As + (wm + t * 16 + l15) * 32 + quad * 8);
            bfr[t] = *(const bf16x8*)(Bs + (wn + t * 16 + l15) * 32 + quad * 8);
        }
        #pragma unroll
        for (int mt = 0; mt < 4; ++mt)
            #pragma unroll
            for (int nt = 0; nt < 4; ++nt)
                acc[mt][nt] = __builtin_amdgcn_mfma_f32_16x16x32_bf16(
                    af[mt], bfr[nt], acc[mt][nt], 0, 0, 0);
        __syncthreads();
    }

    #pragma unroll
    for (int nt = 0; nt < 4; ++nt) {
        const int col = n0 + wn + nt * 16 + l15;
        const float bv = bias[col];
        #pragma unroll
        for (int mt = 0; mt < 4; ++mt) {
            const int rbase = m0 + wm + mt * 16 + quad * 4;
            #pragma unroll
            for (int r = 0; r < 4; ++r)
                out[(rbase + r) * OUT_F + col] = acc[mt][nt][r] + bv;
        }
    }
}

extern "C" void kernel_launch(void* const* d_in, const int* in_sizes, int n_in,
                              void* d_out, int out_size, void* d_ws, size_t ws_size,
                              hipStream_t stream)
{
    const float* x      = (const float*)d_in[0];  // (4096, 4096)
    const float* weight = (const float*)d_in[1];  // (4096, 4096)
    const float* bias   = (const float*)d_in[2];  // (4096,)
    float* out = (float*)d_out;                   // (4096, 4096) f32

    bf16* xs  = (bf16*)d_ws;                      // 4096*256 bf16 = 2 MB
    bf16* wsT = xs + 4096 * 256;                  // 4096*256 bf16 = 2 MB

    reduce_kernel<<<8192, 256, 0, stream>>>(x, weight, xs, wsT);
    gemm_bt_kernel<<<dim3(32, 32), 256, 0, stream>>>(xs, wsT, bias, out);
}

// Round 5
// 189.810 us; speedup vs baseline: 1.0002x; 1.0002x over previous
//
#include <hip/hip_runtime.h>

// Problem constants
#define H_ROWS 4096
#define IN_F   4096
#define OUT_F  4096

typedef __bf16 bf16;
typedef __bf16 bf16x4 __attribute__((ext_vector_type(4)));
typedef __bf16 bf16x8 __attribute__((ext_vector_type(8)));
typedef float  f32x4  __attribute__((ext_vector_type(4)));

// ---------------------------------------------------------------------------
// Kernel 1 (R5): ONE matrix per dispatch (pure stream), 2 adjacent rows per
// block = one contiguous 32 KB global read, staged via fire-and-forget
// global_load_lds (no data VGPRs, no dependency chain, 8 loads/thread in
// flight; 32 KB LDS -> 5 blocks/CU -> ~160 KB outstanding per CU).
// Launched twice: (x -> xs) and (weight -> wsT).
//   Output: dst[r][t] = sum_{v=0..15} src[r][v*256+t],  t in [0,256).
// R1-R4 lesson: 4 different structures all pinned at ~52us / 2.4 TB/s for
// the mixed 128MB reduce; this round unmixes the streams and halves each
// dispatch so the gemm becomes visible in the profile.
// ---------------------------------------------------------------------------
__global__ __launch_bounds__(256) void reduce2_kernel(
    const float* __restrict__ src, bf16* __restrict__ dst)
{
    __shared__ float stage[8192];    // 32 KB: rows 2b and 2b+1, contiguous
    const int b   = blockIdx.x;      // 0..2047
    const int tid = threadIdx.x;
    const int r0  = b * 2;

    const float* __restrict__ base = src + (size_t)r0 * IN_F;
    #pragma unroll
    for (int c = 0; c < 8; ++c) {
        const int f = c * 256 + tid;     // float4 index in [0,2048)
        __builtin_amdgcn_global_load_lds(
            (const __attribute__((address_space(1))) void*)(base + f * 4),
            (__attribute__((address_space(3))) void*)(stage + f * 4), 16, 0, 0);
    }
    __syncthreads();   // vmcnt drain

    // Two outputs per thread (one per row). LDS reads: lanes hit bank
    // (tid mod 32) -> 2-way aliasing across the wave = free.
    float s0 = 0.f, s1 = 0.f;
    #pragma unroll
    for (int v = 0; v < 16; ++v) {
        s0 += stage[v * 256 + tid];
        s1 += stage[4096 + v * 256 + tid];
    }
    dst[r0 * 256 + tid]       = (bf16)s0;
    dst[(r0 + 1) * 256 + tid] = (bf16)s1;
}

// ---------------------------------------------------------------------------
// Kernel 2: NT GEMM  out[m][n] = sum_k A[m][k]*B[n][k] + bias[n]
//   A = xs  (M=4096, K=256) bf16 row-major
//   B = wsT (N=4096, K=256) bf16 row-major
// m97 structure: 128x128 block tile, BK=32, global_load_lds width=16,
// 4 waves in 2x2, each wave 64x64 = 4x4 tiles of 16x16x32 MFMA.
// (unchanged — waiting for its first profile appearance before touching it)
// ---------------------------------------------------------------------------
__global__ __launch_bounds__(256) void gemm_bt_kernel(
    const bf16* __restrict__ A, const bf16* __restrict__ B,
    const float* __restrict__ bias, float* __restrict__ out)
{
    __shared__ bf16 As[128 * 32];   // 8 KB
    __shared__ bf16 Bs[128 * 32];   // 8 KB

    const int m0   = blockIdx.y * 128;
    const int n0   = blockIdx.x * 128;
    const int tid  = threadIdx.x;
    const int lane = tid & 63;
    const int w    = tid >> 6;
    const int wm   = (w & 1) * 64;
    const int wn   = (w >> 1) * 64;
    const int l15  = lane & 15;
    const int quad = lane >> 4;

    f32x4 acc[4][4] = {};

    for (int kk = 0; kk < 8; ++kk) {
        const int k0 = kk * 32;
        #pragma unroll
        for (int c = 0; c < 2; ++c) {
            const int chunk = c * 256 + tid;
            const int row   = chunk >> 2;      // 0..127
            const int kc    = chunk & 3;       // 16B chunk within 64B row
            const bf16* ga = A + (m0 + row) * 256 + k0 + kc * 8;
            const bf16* gb = B + (n0 + row) * 256 + k0 + kc * 8;
            __builtin_amdgcn_global_load_lds(
                (const __attribute__((address_space(1))) void*)ga,
                (__attribute__((address_space(3))) void*)(As + chunk * 8), 16, 0, 0);
            __builtin_amdgcn_global_load_lds(
                (const __attribute__((address_space(1))) void*)gb,
                (__attribute__((address_space(3))) void*)(Bs + chunk * 8), 16, 0, 0);
        }
        __syncthreads();

        bf16x8 af[4], bfr[4];
        #pragma unroll
        for (int t = 0; t < 4; ++t) {
            af[t]  = *(const bf16x8*)(As + (wm + t * 16 + l15) * 32 + quad * 8);
            bfr[t] = *(const bf16x8*)(Bs + (wn + t * 16 + l15) * 32 + quad * 8);
        }
        #pragma unroll
        for (int mt = 0; mt < 4; ++mt)
            #pragma unroll
            for (int nt = 0; nt < 4; ++nt)
                acc[mt][nt] = __builtin_amdgcn_mfma_f32_16x16x32_bf16(
                    af[mt], bfr[nt], acc[mt][nt], 0, 0, 0);
        __syncthreads();
    }

    #pragma unroll
    for (int nt = 0; nt < 4; ++nt) {
        const int col = n0 + wn + nt * 16 + l15;
        const float bv = bias[col];
        #pragma unroll
        for (int mt = 0; mt < 4; ++mt) {
            const int rbase = m0 + wm + mt * 16 + quad * 4;
            #pragma unroll
            for (int r = 0; r < 4; ++r)
                out[(rbase + r) * OUT_F + col] = acc[mt][nt][r] + bv;
        }
    }
}

extern "C" void kernel_launch(void* const* d_in, const int* in_sizes, int n_in,
                              void* d_out, int out_size, void* d_ws, size_t ws_size,
                              hipStream_t stream)
{
    const float* x      = (const float*)d_in[0];  // (4096, 4096)
    const float* weight = (const float*)d_in[1];  // (4096, 4096)
    const float* bias   = (const float*)d_in[2];  // (4096,)
    float* out = (float*)d_out;                   // (4096, 4096) f32

    bf16* xs  = (bf16*)d_ws;                      // 4096*256 bf16 = 2 MB
    bf16* wsT = xs + 4096 * 256;                  // 4096*256 bf16 = 2 MB

    reduce2_kernel<<<2048, 256, 0, stream>>>(x, xs);
    reduce2_kernel<<<2048, 256, 0, stream>>>(weight, wsT);
    gemm_bt_kernel<<<dim3(32, 32), 256, 0, stream>>>(xs, wsT, bias, out);
}